// Round 4
// baseline (32880.682 us; speedup 1.0000x reference)
//
#include <hip/hip_runtime.h>
#include <hip/hip_bf16.h>
#include <math.h>

#define BB 4
#define TT 2048
#define VV 99
#define DD 512
#define HH 8
#define LL 6
#define DHH 64
#define OFFS 28
#define ROWS (BB*TT)   // 8192

typedef __hip_bfloat16 bf16;
__device__ __forceinline__ float b2f(bf16 x){ return __bfloat162float(x); }

// mode-dispatched weight read from a raw base + element offset (mode1 = bf16 inputs)
__device__ __forceinline__ float wget(const void* w, int mode, size_t i){
    return mode ? b2f(((const bf16*)w)[i]) : ((const float*)w)[i];
}

// ---------------- init: zero loss acc + detect input dtype ----------------
// ln1_w is all-ones: fp32 -> first word 0x3F800000; bf16 -> 0x3F803F80.
__global__ void init_kernel(const unsigned int* __restrict__ ln1_bits, float* __restrict__ acc,
                            int* __restrict__ flag){
    acc[0] = 0.f; acc[1] = 0.f;
    flag[0] = (ln1_bits[0] == 0x3F800000u) ? 0 : 1;
}

// ---------------- embedding: x = wte[idx] + wpe[t] ----------------
__global__ void embed_kernel(const int* __restrict__ idx, const void* __restrict__ wte,
                             const void* __restrict__ wpe, float* __restrict__ x,
                             const int* __restrict__ flag){
    int mode = flag[0];
    int row = blockIdx.x;          // b*T + t
    int t = row % TT;
    int tok = idx[row];
    int i = threadIdx.x;           // 0..255
    #pragma unroll
    for (int j = 0; j < 2; ++j){
        int d = i + j*256;
        x[(size_t)row*DD + d] = wget(wte, mode, (size_t)tok*DD + d)
                              + wget(wpe, mode, (size_t)t*DD + d);
    }
}

// ---------------- layernorm: fp32 in, bf16 out; weight element row offset woff ----------------
__global__ void ln_kernel(const float* __restrict__ x, const void* __restrict__ w,
                          size_t woff, bf16* __restrict__ out, const int* __restrict__ flag){
    int mode = flag[0];
    int row = blockIdx.x;
    int lane = threadIdx.x; // 64
    const float* xr = x + (size_t)row*DD;
    float v[8];
    float s = 0.f;
    #pragma unroll
    for (int j=0;j<8;++j){ v[j] = xr[lane + j*64]; s += v[j]; }
    #pragma unroll
    for (int o=32;o;o>>=1) s += __shfl_xor(s,o);
    float mean = s * (1.0f/DD);
    float vs = 0.f;
    #pragma unroll
    for (int j=0;j<8;++j){ float d = v[j]-mean; vs += d*d; }
    #pragma unroll
    for (int o=32;o;o>>=1) vs += __shfl_xor(vs,o);
    float rstd = rsqrtf(vs*(1.0f/DD) + 1e-5f);
    #pragma unroll
    for (int j=0;j<8;++j){
        int d = lane + j*64;
        out[(size_t)row*DD + d] = __float2bfloat16((v[j]-mean)*rstd*wget(w,mode,woff+d));
    }
}

// ---------------- GEMM: C[M,N] = A[M,K] @ W[N,K]^T ----------------
// A bf16 (activations), W raw weights (mode dtype), weight element offset woff.
// EPI: 0 = bf16 store Cb, 1 = fp32 += C (residual), 2 = gelu -> bf16 Cb, 3 = fp32 store C
template<int EPI>
__global__ __launch_bounds__(256) void gemm_nt(const bf16* __restrict__ A,
        const void* __restrict__ W, size_t woff, float* __restrict__ C, bf16* __restrict__ Cb,
        int M, int N, int K, const int* __restrict__ flag){
    int mode = flag[0];
    __shared__ float As[16][64];
    __shared__ float Ws[16][64];
    int m0 = blockIdx.y * 64;
    int n0 = blockIdx.x * 64;
    int t = threadIdx.x;
    int tx = t & 15, ty = t >> 4;
    float acc[4][4] = {};
    int am = t >> 2;            // 0..63
    int ak = (t & 3) * 4;       // 0,4,8,12

    for (int k0 = 0; k0 < K; k0 += 16){
        {
            const __hip_bfloat162* ap = (const __hip_bfloat162*)(A + (size_t)(m0+am)*K + k0 + ak);
            __hip_bfloat162 p0 = ap[0], p1 = ap[1];
            float2 f0 = __bfloat1622float2(p0), f1 = __bfloat1622float2(p1);
            As[ak+0][am]=f0.x; As[ak+1][am]=f0.y; As[ak+2][am]=f1.x; As[ak+3][am]=f1.y;
        }
        int wn = n0 + am;
        if (wn < N){
            size_t off = woff + (size_t)wn*K + k0 + ak;
            if (mode == 0){
                float4 wv = *(const float4*)((const float*)W + off);
                Ws[ak+0][am]=wv.x; Ws[ak+1][am]=wv.y; Ws[ak+2][am]=wv.z; Ws[ak+3][am]=wv.w;
            } else {
                const __hip_bfloat162* wp = (const __hip_bfloat162*)((const bf16*)W + off);
                __hip_bfloat162 p0 = wp[0], p1 = wp[1];
                float2 f0 = __bfloat1622float2(p0), f1 = __bfloat1622float2(p1);
                Ws[ak+0][am]=f0.x; Ws[ak+1][am]=f0.y; Ws[ak+2][am]=f1.x; Ws[ak+3][am]=f1.y;
            }
        } else {
            Ws[ak+0][am]=0.f; Ws[ak+1][am]=0.f; Ws[ak+2][am]=0.f; Ws[ak+3][am]=0.f;
        }
        __syncthreads();
        #pragma unroll
        for (int kk=0;kk<16;++kk){
            float a[4], b[4];
            #pragma unroll
            for (int i=0;i<4;++i) a[i]=As[kk][ty*4+i];
            #pragma unroll
            for (int j=0;j<4;++j) b[j]=Ws[kk][tx*4+j];
            #pragma unroll
            for (int i=0;i<4;++i)
                #pragma unroll
                for (int j=0;j<4;++j)
                    acc[i][j] += a[i]*b[j];
        }
        __syncthreads();
    }

    #pragma unroll
    for (int i=0;i<4;++i){
        int m = m0 + ty*4 + i;
        #pragma unroll
        for (int j=0;j<4;++j){
            int n = n0 + tx*4 + j;
            if (n >= N) continue;
            float val = acc[i][j];
            if (EPI==0){
                Cb[(size_t)m*N+n] = __float2bfloat16(val);
            } else if (EPI==1){
                C[(size_t)m*N+n] += val;
            } else if (EPI==2){
                float xx = val;
                float u = 0.7978845608028654f*(xx + 0.044715f*xx*xx*xx);
                Cb[(size_t)m*N+n] = __float2bfloat16(0.5f*xx*(1.0f+tanhf(u)));
            } else {
                C[(size_t)m*N+n] = val;   // fp32 logits
            }
        }
    }
}

// ---------------- attention: one wave per (b,h,q), online softmax ----------------
__global__ void attn_kernel(const bf16* __restrict__ qkv, bf16* __restrict__ y){
    int lane = threadIdx.x;              // d within head
    int q = blockIdx.x % TT;
    int bh = blockIdx.x / TT;
    int h = bh % HH;
    int b = bh / HH;
    const int RS = 3*DD;                 // 1536
    size_t brow = (size_t)(b*TT);
    float qv = b2f(qkv[(brow + q)*RS + h*DHH + lane]) * 0.125f;
    const bf16* kbase = qkv + brow*RS + DD   + h*DHH + lane;
    const bf16* vbase = qkv + brow*RS + 2*DD + h*DHH + lane;
    float m = -1e30f, s = 0.f, acc = 0.f;
    int jmax = q + OFFS; if (jmax > TT-1) jmax = TT-1;
    for (int j = 0; j <= jmax; ++j){
        float kv = b2f(kbase[(size_t)j*RS]);
        float p = qv*kv;
        #pragma unroll
        for (int o=32;o;o>>=1) p += __shfl_xor(p,o);
        float vv = b2f(vbase[(size_t)j*RS]);
        float nm = fmaxf(m, p);
        float alpha = __expf(m - nm);
        float w = __expf(p - nm);
        s = s*alpha + w;
        acc = acc*alpha + w*vv;
        m = nm;
    }
    y[(brow + q)*DD + h*DHH + lane] = __float2bfloat16(acc / s);
}

// ---------------- loss (fp32 logits) ----------------
__global__ void loss_kernel(const float* __restrict__ logits, const int* __restrict__ targets,
                            float* __restrict__ acc){
    int row = blockIdx.x;
    int lane = threadIdx.x;
    int yt = targets[row];
    const float* lp = logits + (size_t)row*VV;
    float e0 = (lane < VV)    ? lp[lane]    : -1e30f;
    float e1 = (lane+64 < VV) ? lp[lane+64] : -1e30f;
    float mx = fmaxf(e0,e1);
    #pragma unroll
    for (int o=32;o;o>>=1) mx = fmaxf(mx, __shfl_xor(mx,o));
    float se = 0.f;
    if (lane < VV)    se += __expf(e0-mx);
    if (lane+64 < VV) se += __expf(e1-mx);
    #pragma unroll
    for (int o=32;o;o>>=1) se += __shfl_xor(se,o);
    if (lane == 0 && yt >= 0){
        float wi = (yt>=78 && yt<96) ? 1.0f : (yt==96 ? 0.1f : 0.0f);
        if (wi > 0.f){
            float ly = lp[yt];
            float nll = -(ly - mx - logf(se));
            atomicAdd(&acc[0], wi*nll);
            atomicAdd(&acc[1], wi);
        }
    }
}

__global__ void fin_loss(const float* __restrict__ acc, float* __restrict__ out){
    out[0] = acc[0]/acc[1];
}

// ---------------- launch ----------------
extern "C" void kernel_launch(void* const* d_in, const int* in_sizes, int n_in,
                              void* d_out, int out_size, void* d_ws, size_t ws_size,
                              hipStream_t stream){
    const int*  idx     = (const int*) d_in[0];
    const int*  targets = (const int*) d_in[1];
    const void* wte     = d_in[2];
    const void* wpe     = d_in[3];
    const void* ln1_w   = d_in[4];
    const void* attn_w  = d_in[5];
    const void* proj_w  = d_in[6];
    const void* ln2_w   = d_in[7];
    const void* fc_w    = d_in[8];
    const void* fcp_w   = d_in[9];
    const void* lnf_w   = d_in[10];
    float* out = (float*)d_out;   // fp32: logits [8192,99] then loss [1]

    // workspace layout (float-slot offsets). Total ~56 MB.
    float* ws   = (float*)d_ws;
    float* ACC  = ws;                                    // 2 floats
    int*   FLAG = (int*)(ws + 4);
    bf16*  Hb   = (bf16*)(ws + 16);                      // [8192,512] bf16 (8 MB)
    float* X    = ws + 16 + 2097152;                     // [8192,512] fp32 (16 MB)
    bf16*  BIG  = (bf16*)(ws + 16 + 2097152 + 4194304);  // [8192,2048] bf16 (32 MB)

    const size_t ATT_S = (size_t)3*DD*DD;
    const size_t PRJ_S = (size_t)DD*DD;
    const size_t FC_S  = (size_t)4*DD*DD;

    init_kernel<<<1,1,0,stream>>>((const unsigned int*)ln1_w, ACC, FLAG);
    embed_kernel<<<ROWS,256,0,stream>>>(idx, wte, wpe, X, FLAG);
    for (int l=0; l<LL; ++l){
        ln_kernel<<<ROWS,64,0,stream>>>(X, ln1_w, (size_t)l*DD, Hb, FLAG);
        gemm_nt<0><<<dim3(3*DD/64, ROWS/64),256,0,stream>>>(Hb, attn_w, (size_t)l*ATT_S,
                                                            nullptr, BIG, ROWS, 3*DD, DD, FLAG);
        attn_kernel<<<BB*HH*TT,64,0,stream>>>(BIG, Hb);
        gemm_nt<1><<<dim3(DD/64, ROWS/64),256,0,stream>>>(Hb, proj_w, (size_t)l*PRJ_S,
                                                          X, nullptr, ROWS, DD, DD, FLAG);
        ln_kernel<<<ROWS,64,0,stream>>>(X, ln2_w, (size_t)l*DD, Hb, FLAG);
        gemm_nt<2><<<dim3(4*DD/64, ROWS/64),256,0,stream>>>(Hb, fc_w, (size_t)l*FC_S,
                                                            nullptr, BIG, ROWS, 4*DD, DD, FLAG);
        gemm_nt<1><<<dim3(DD/64, ROWS/64),256,0,stream>>>(BIG, fcp_w, (size_t)l*FC_S,
                                                          X, nullptr, ROWS, DD, 4*DD, FLAG);
    }
    ln_kernel<<<ROWS,64,0,stream>>>(X, lnf_w, 0, Hb, FLAG);
    gemm_nt<3><<<dim3((VV+63)/64, ROWS/64),256,0,stream>>>(Hb, wte, 0, out, nullptr, ROWS, VV, DD, FLAG);
    loss_kernel<<<ROWS,64,0,stream>>>(out, targets, ACC);
    fin_loss<<<1,1,0,stream>>>(ACC, out + (size_t)ROWS*VV);
}

// Round 5
// 7627.176 us; speedup vs baseline: 4.3110x; 4.3110x over previous
//
#include <hip/hip_runtime.h>
#include <hip/hip_bf16.h>
#include <math.h>

#define BB 4
#define TT 2048
#define VV 99
#define DD 512
#define HH 8
#define LL 6
#define DHH 64
#define OFFS 28
#define ROWS (BB*TT)   // 8192

typedef __hip_bfloat16 bf16;
__device__ __forceinline__ float b2f(bf16 x){ return __bfloat162float(x); }

// mode-dispatched weight read from a raw base + element offset (mode1 = bf16 inputs)
__device__ __forceinline__ float wget(const void* w, int mode, size_t i){
    return mode ? b2f(((const bf16*)w)[i]) : ((const float*)w)[i];
}

__device__ __forceinline__ void unpack8(uint4 w, float* f){
    unsigned int a[4] = {w.x, w.y, w.z, w.w};
    #pragma unroll
    for (int k=0;k<4;++k){
        f[2*k]   = __uint_as_float((a[k] & 0xFFFFu) << 16);
        f[2*k+1] = __uint_as_float(a[k] & 0xFFFF0000u);
    }
}

// ---------------- init: zero loss acc + detect input dtype ----------------
__global__ void init_kernel(const unsigned int* __restrict__ ln1_bits, float* __restrict__ acc,
                            int* __restrict__ flag){
    acc[0] = 0.f; acc[1] = 0.f;
    flag[0] = (ln1_bits[0] == 0x3F800000u) ? 0 : 1;
}

// ---------------- embedding: x = wte[idx] + wpe[t] ----------------
__global__ void embed_kernel(const int* __restrict__ idx, const void* __restrict__ wte,
                             const void* __restrict__ wpe, float* __restrict__ x,
                             const int* __restrict__ flag){
    int mode = flag[0];
    int row = blockIdx.x;
    int t = row % TT;
    int tok = idx[row];
    int i = threadIdx.x;
    #pragma unroll
    for (int j = 0; j < 2; ++j){
        int d = i + j*256;
        x[(size_t)row*DD + d] = wget(wte, mode, (size_t)tok*DD + d)
                              + wget(wpe, mode, (size_t)t*DD + d);
    }
}

// ---------------- layernorm: fp32 in, bf16 out ----------------
__global__ void ln_kernel(const float* __restrict__ x, const void* __restrict__ w,
                          size_t woff, bf16* __restrict__ out, const int* __restrict__ flag){
    int mode = flag[0];
    int row = blockIdx.x;
    int lane = threadIdx.x; // 64
    const float* xr = x + (size_t)row*DD;
    float v[8];
    float s = 0.f;
    #pragma unroll
    for (int j=0;j<8;++j){ v[j] = xr[lane + j*64]; s += v[j]; }
    #pragma unroll
    for (int o=32;o;o>>=1) s += __shfl_xor(s,o);
    float mean = s * (1.0f/DD);
    float vs = 0.f;
    #pragma unroll
    for (int j=0;j<8;++j){ float d = v[j]-mean; vs += d*d; }
    #pragma unroll
    for (int o=32;o;o>>=1) vs += __shfl_xor(vs,o);
    float rstd = rsqrtf(vs*(1.0f/DD) + 1e-5f);
    #pragma unroll
    for (int j=0;j<8;++j){
        int d = lane + j*64;
        out[(size_t)row*DD + d] = __float2bfloat16((v[j]-mean)*rstd*wget(w,mode,woff+d));
    }
}

// ---------------- GEMM: C[M,N] = A[M,K] @ W[N,K]^T ----------------
// EPI: 0 = bf16 store Cb, 1 = fp32 += C (residual), 2 = gelu -> bf16 Cb, 3 = fp32 store C
template<int EPI>
__global__ __launch_bounds__(256) void gemm_nt(const bf16* __restrict__ A,
        const void* __restrict__ W, size_t woff, float* __restrict__ C, bf16* __restrict__ Cb,
        int M, int N, int K, const int* __restrict__ flag){
    int mode = flag[0];
    __shared__ float As[16][64];
    __shared__ float Ws[16][64];
    int m0 = blockIdx.y * 64;
    int n0 = blockIdx.x * 64;
    int t = threadIdx.x;
    int tx = t & 15, ty = t >> 4;
    float acc[4][4] = {};
    int am = t >> 2;
    int ak = (t & 3) * 4;

    for (int k0 = 0; k0 < K; k0 += 16){
        {
            const __hip_bfloat162* ap = (const __hip_bfloat162*)(A + (size_t)(m0+am)*K + k0 + ak);
            __hip_bfloat162 p0 = ap[0], p1 = ap[1];
            float2 f0 = __bfloat1622float2(p0), f1 = __bfloat1622float2(p1);
            As[ak+0][am]=f0.x; As[ak+1][am]=f0.y; As[ak+2][am]=f1.x; As[ak+3][am]=f1.y;
        }
        int wn = n0 + am;
        if (wn < N){
            size_t off = woff + (size_t)wn*K + k0 + ak;
            if (mode == 0){
                float4 wv = *(const float4*)((const float*)W + off);
                Ws[ak+0][am]=wv.x; Ws[ak+1][am]=wv.y; Ws[ak+2][am]=wv.z; Ws[ak+3][am]=wv.w;
            } else {
                const __hip_bfloat162* wp = (const __hip_bfloat162*)((const bf16*)W + off);
                __hip_bfloat162 p0 = wp[0], p1 = wp[1];
                float2 f0 = __bfloat1622float2(p0), f1 = __bfloat1622float2(p1);
                Ws[ak+0][am]=f0.x; Ws[ak+1][am]=f0.y; Ws[ak+2][am]=f1.x; Ws[ak+3][am]=f1.y;
            }
        } else {
            Ws[ak+0][am]=0.f; Ws[ak+1][am]=0.f; Ws[ak+2][am]=0.f; Ws[ak+3][am]=0.f;
        }
        __syncthreads();
        #pragma unroll
        for (int kk=0;kk<16;++kk){
            float a[4], b[4];
            #pragma unroll
            for (int i=0;i<4;++i) a[i]=As[kk][ty*4+i];
            #pragma unroll
            for (int j=0;j<4;++j) b[j]=Ws[kk][tx*4+j];
            #pragma unroll
            for (int i=0;i<4;++i)
                #pragma unroll
                for (int j=0;j<4;++j)
                    acc[i][j] += a[i]*b[j];
        }
        __syncthreads();
    }

    #pragma unroll
    for (int i=0;i<4;++i){
        int m = m0 + ty*4 + i;
        #pragma unroll
        for (int j=0;j<4;++j){
            int n = n0 + tx*4 + j;
            if (n >= N) continue;
            float val = acc[i][j];
            if (EPI==0){
                Cb[(size_t)m*N+n] = __float2bfloat16(val);
            } else if (EPI==1){
                C[(size_t)m*N+n] += val;
            } else if (EPI==2){
                float xx = val;
                float u = 0.7978845608028654f*(xx + 0.044715f*xx*xx*xx);
                Cb[(size_t)m*N+n] = __float2bfloat16(0.5f*xx*(1.0f+tanhf(u)));
            } else {
                C[(size_t)m*N+n] = val;
            }
        }
    }
}

// ---------------- attention v2: tiled flash, one wg per (b,h,qtile64) ----------------
// qkv bf16 [B,T,3D]; y bf16 [B,T,D]
__global__ __launch_bounds__(256) void attn_kernel2(const bf16* __restrict__ qkv,
                                                    bf16* __restrict__ y){
    __shared__ float Qst[64*68];   // Q^T: [d][q], pre-scaled
    __shared__ float KPs[64*68];   // K^T: [d][j]; reused as P: [q][j]
    __shared__ float Vs [64*68];   // V:   [j][d]

    int tid = threadIdx.x;
    int tx = tid & 15, ty = tid >> 4;
    int bi = blockIdx.x;
    int qt = 31 - (bi & 31);       // big tiles first
    int bh = bi >> 5;
    int h = bh & 7;
    int b = bh >> 3;
    int q0 = qt * 64;
    size_t base = (size_t)b * TT * 1536;

    int r  = tid >> 2;             // 0..63: row within tile
    int dc = (tid & 3) << 4;       // 0,16,32,48: d-chunk

    // stage Q transposed + scaled
    {
        const uint4* gp = (const uint4*)(qkv + base + (size_t)(q0 + r)*1536 + h*64 + dc);
        uint4 w0 = gp[0], w1 = gp[1];
        float f[16];
        unpack8(w0, f); unpack8(w1, f+8);
        #pragma unroll
        for (int k=0;k<16;++k) Qst[(dc+k)*68 + r] = f[k] * 0.125f;
    }

    float acc[4][4] = {};
    float mrow[4] = {-1e30f,-1e30f,-1e30f,-1e30f};
    float lrow[4] = {0.f,0.f,0.f,0.f};

    int jbmax = qt + 1; if (jbmax > 31) jbmax = 31;

    for (int jb = 0; jb <= jbmax; ++jb){
        int j0 = jb * 64;
        __syncthreads();   // previous iteration's P/V reads done
        // stage K transposed and V
        {
            const uint4* gp = (const uint4*)(qkv + base + (size_t)(j0 + r)*1536 + DD + h*64 + dc);
            uint4 w0 = gp[0], w1 = gp[1];
            float f[16];
            unpack8(w0, f); unpack8(w1, f+8);
            #pragma unroll
            for (int k=0;k<16;++k) KPs[(dc+k)*68 + r] = f[k];
        }
        {
            const uint4* gp = (const uint4*)(qkv + base + (size_t)(j0 + r)*1536 + 2*DD + h*64 + dc);
            uint4 w0 = gp[0], w1 = gp[1];
            float f[16];
            unpack8(w0, f); unpack8(w1, f+8);
            #pragma unroll
            for (int k4=0;k4<4;++k4)
                *(float4*)&Vs[r*68 + dc + k4*4] = *(float4*)&f[k4*4];
        }
        __syncthreads();

        // S = Q K^T for this tile: 4x4 per thread
        float s[4][4] = {};
        #pragma unroll 8
        for (int d=0; d<64; ++d){
            float a[4], bb[4];
            *(float4*)a  = *(float4*)&Qst[d*68 + ty*4];
            *(float4*)bb = *(float4*)&KPs[d*68 + tx*4];
            #pragma unroll
            for (int i=0;i<4;++i)
                #pragma unroll
                for (int j=0;j<4;++j)
                    s[i][j] += a[i]*bb[j];
        }

        // mask (only for partial blocks)
        if (j0 + 63 > q0 + OFFS){
            #pragma unroll
            for (int i=0;i<4;++i){
                int qg = q0 + ty*4 + i;
                #pragma unroll
                for (int j=0;j<4;++j){
                    if (j0 + tx*4 + j > qg + OFFS) s[i][j] = -1e30f;
                }
            }
        }

        // online softmax update (state replicated across the 16 tx lanes of each row)
        float bm[4], rs[4], alpha[4];
        #pragma unroll
        for (int i=0;i<4;++i){
            bm[i] = fmaxf(fmaxf(s[i][0], s[i][1]), fmaxf(s[i][2], s[i][3]));
        }
        #pragma unroll
        for (int o=1;o<16;o<<=1){
            #pragma unroll
            for (int i=0;i<4;++i) bm[i] = fmaxf(bm[i], __shfl_xor(bm[i], o));
        }
        #pragma unroll
        for (int i=0;i<4;++i){
            float nm = fmaxf(mrow[i], bm[i]);
            alpha[i] = __expf(mrow[i] - nm);
            mrow[i] = nm;
            rs[i] = 0.f;
            #pragma unroll
            for (int j=0;j<4;++j){
                s[i][j] = __expf(s[i][j] - nm);
                rs[i] += s[i][j];
            }
        }
        #pragma unroll
        for (int o=1;o<16;o<<=1){
            #pragma unroll
            for (int i=0;i<4;++i) rs[i] += __shfl_xor(rs[i], o);
        }
        #pragma unroll
        for (int i=0;i<4;++i){
            lrow[i] = lrow[i]*alpha[i] + rs[i];
            #pragma unroll
            for (int j=0;j<4;++j) acc[i][j] *= alpha[i];
        }

        __syncthreads();   // all waves done reading KPs (as K)
        // write P into KPs space: P[q][j]
        #pragma unroll
        for (int i=0;i<4;++i)
            *(float4*)&KPs[(ty*4+i)*68 + tx*4] = *(float4*)&s[i][0];
        __syncthreads();

        // O += P V : loop over j
        #pragma unroll 8
        for (int j64=0; j64<64; ++j64){
            float vb[4];
            *(float4*)vb = *(float4*)&Vs[j64*68 + tx*4];
            float p[4];
            #pragma unroll
            for (int i=0;i<4;++i) p[i] = KPs[(ty*4+i)*68 + j64];
            #pragma unroll
            for (int i=0;i<4;++i)
                #pragma unroll
                for (int j=0;j<4;++j)
                    acc[i][j] += p[i]*vb[j];
        }
    }

    // epilogue: O / l -> y
    #pragma unroll
    for (int i=0;i<4;++i){
        int qg = q0 + ty*4 + i;
        float inv = 1.0f / lrow[i];
        bf16* yp = y + ((size_t)b*TT + qg)*DD + h*64 + tx*4;
        #pragma unroll
        for (int j=0;j<4;++j) yp[j] = __float2bfloat16(acc[i][j]*inv);
    }
}

// ---------------- loss (fp32 logits) ----------------
__global__ void loss_kernel(const float* __restrict__ logits, const int* __restrict__ targets,
                            float* __restrict__ acc){
    int row = blockIdx.x;
    int lane = threadIdx.x;
    int yt = targets[row];
    const float* lp = logits + (size_t)row*VV;
    float e0 = (lane < VV)    ? lp[lane]    : -1e30f;
    float e1 = (lane+64 < VV) ? lp[lane+64] : -1e30f;
    float mx = fmaxf(e0,e1);
    #pragma unroll
    for (int o=32;o;o>>=1) mx = fmaxf(mx, __shfl_xor(mx,o));
    float se = 0.f;
    if (lane < VV)    se += __expf(e0-mx);
    if (lane+64 < VV) se += __expf(e1-mx);
    #pragma unroll
    for (int o=32;o;o>>=1) se += __shfl_xor(se,o);
    if (lane == 0 && yt >= 0){
        float wi = (yt>=78 && yt<96) ? 1.0f : (yt==96 ? 0.1f : 0.0f);
        if (wi > 0.f){
            float ly = lp[yt];
            float nll = -(ly - mx - logf(se));
            atomicAdd(&acc[0], wi*nll);
            atomicAdd(&acc[1], wi);
        }
    }
}

__global__ void fin_loss(const float* __restrict__ acc, float* __restrict__ out){
    out[0] = acc[0]/acc[1];
}

// ---------------- launch ----------------
extern "C" void kernel_launch(void* const* d_in, const int* in_sizes, int n_in,
                              void* d_out, int out_size, void* d_ws, size_t ws_size,
                              hipStream_t stream){
    const int*  idx     = (const int*) d_in[0];
    const int*  targets = (const int*) d_in[1];
    const void* wte     = d_in[2];
    const void* wpe     = d_in[3];
    const void* ln1_w   = d_in[4];
    const void* attn_w  = d_in[5];
    const void* proj_w  = d_in[6];
    const void* ln2_w   = d_in[7];
    const void* fc_w    = d_in[8];
    const void* fcp_w   = d_in[9];
    const void* lnf_w   = d_in[10];
    float* out = (float*)d_out;   // fp32: logits [8192,99] then loss [1]

    float* ws   = (float*)d_ws;
    float* ACC  = ws;
    int*   FLAG = (int*)(ws + 4);
    bf16*  Hb   = (bf16*)(ws + 16);                      // [8192,512] bf16
    float* X    = ws + 16 + 2097152;                     // [8192,512] fp32
    bf16*  BIG  = (bf16*)(ws + 16 + 2097152 + 4194304);  // [8192,2048] bf16

    const size_t ATT_S = (size_t)3*DD*DD;
    const size_t PRJ_S = (size_t)DD*DD;
    const size_t FC_S  = (size_t)4*DD*DD;

    init_kernel<<<1,1,0,stream>>>((const unsigned int*)ln1_w, ACC, FLAG);
    embed_kernel<<<ROWS,256,0,stream>>>(idx, wte, wpe, X, FLAG);
    for (int l=0; l<LL; ++l){
        ln_kernel<<<ROWS,64,0,stream>>>(X, ln1_w, (size_t)l*DD, Hb, FLAG);
        gemm_nt<0><<<dim3(3*DD/64, ROWS/64),256,0,stream>>>(Hb, attn_w, (size_t)l*ATT_S,
                                                            nullptr, BIG, ROWS, 3*DD, DD, FLAG);
        attn_kernel2<<<dim3(BB*HH*32),256,0,stream>>>(BIG, Hb);
        gemm_nt<1><<<dim3(DD/64, ROWS/64),256,0,stream>>>(Hb, proj_w, (size_t)l*PRJ_S,
                                                          X, nullptr, ROWS, DD, DD, FLAG);
        ln_kernel<<<ROWS,64,0,stream>>>(X, ln2_w, (size_t)l*DD, Hb, FLAG);
        gemm_nt<2><<<dim3(4*DD/64, ROWS/64),256,0,stream>>>(Hb, fc_w, (size_t)l*FC_S,
                                                            nullptr, BIG, ROWS, 4*DD, DD, FLAG);
        gemm_nt<1><<<dim3(DD/64, ROWS/64),256,0,stream>>>(BIG, fcp_w, (size_t)l*FC_S,
                                                          X, nullptr, ROWS, DD, 4*DD, FLAG);
    }
    ln_kernel<<<ROWS,64,0,stream>>>(X, lnf_w, 0, Hb, FLAG);
    gemm_nt<3><<<dim3((VV+63)/64, ROWS/64),256,0,stream>>>(Hb, wte, 0, out, nullptr, ROWS, VV, DD, FLAG);
    loss_kernel<<<ROWS,64,0,stream>>>(out, targets, ACC);
    fin_loss<<<1,1,0,stream>>>(ACC, out + (size_t)ROWS*VV);
}

// Round 6
// 4269.864 us; speedup vs baseline: 7.7006x; 1.7863x over previous
//
#include <hip/hip_runtime.h>
#include <hip/hip_bf16.h>
#include <math.h>

#define BB 4
#define TT 2048
#define VV 99
#define DD 512
#define HH 8
#define LL 6
#define DHH 64
#define OFFS 28
#define ROWS (BB*TT)   // 8192

typedef __hip_bfloat16 bf16;
typedef __attribute__((ext_vector_type(8))) short bf16x8;
typedef __attribute__((ext_vector_type(4))) float f32x4;

__device__ __forceinline__ float b2f(bf16 x){ return __bfloat162float(x); }

// mode-dispatched weight read from a raw base + element offset (mode1 = bf16 inputs)
__device__ __forceinline__ float wget(const void* w, int mode, size_t i){
    return mode ? b2f(((const bf16*)w)[i]) : ((const float*)w)[i];
}

__device__ __forceinline__ void unpack8(uint4 w, float* f){
    unsigned int a[4] = {w.x, w.y, w.z, w.w};
    #pragma unroll
    for (int k=0;k<4;++k){
        f[2*k]   = __uint_as_float((a[k] & 0xFFFFu) << 16);
        f[2*k+1] = __uint_as_float(a[k] & 0xFFFF0000u);
    }
}

// ---------------- init ----------------
__global__ void init_kernel(const unsigned int* __restrict__ ln1_bits, float* __restrict__ acc,
                            int* __restrict__ flag){
    acc[0] = 0.f; acc[1] = 0.f;
    flag[0] = (ln1_bits[0] == 0x3F800000u) ? 0 : 1;
}

// ---------------- embedding ----------------
__global__ void embed_kernel(const int* __restrict__ idx, const void* __restrict__ wte,
                             const void* __restrict__ wpe, float* __restrict__ x,
                             const int* __restrict__ flag){
    int mode = flag[0];
    int row = blockIdx.x;
    int t = row % TT;
    int tok = idx[row];
    int i = threadIdx.x;
    #pragma unroll
    for (int j = 0; j < 2; ++j){
        int d = i + j*256;
        x[(size_t)row*DD + d] = wget(wte, mode, (size_t)tok*DD + d)
                              + wget(wpe, mode, (size_t)t*DD + d);
    }
}

// ---------------- layernorm: fp32 in, bf16 out ----------------
__global__ void ln_kernel(const float* __restrict__ x, const void* __restrict__ w,
                          size_t woff, bf16* __restrict__ out, const int* __restrict__ flag){
    int mode = flag[0];
    int row = blockIdx.x;
    int lane = threadIdx.x; // 64
    const float* xr = x + (size_t)row*DD;
    float v[8];
    float s = 0.f;
    #pragma unroll
    for (int j=0;j<8;++j){ v[j] = xr[lane + j*64]; s += v[j]; }
    #pragma unroll
    for (int o=32;o;o>>=1) s += __shfl_xor(s,o);
    float mean = s * (1.0f/DD);
    float vs = 0.f;
    #pragma unroll
    for (int j=0;j<8;++j){ float d = v[j]-mean; vs += d*d; }
    #pragma unroll
    for (int o=32;o;o>>=1) vs += __shfl_xor(vs,o);
    float rstd = rsqrtf(vs*(1.0f/DD) + 1e-5f);
    #pragma unroll
    for (int j=0;j<8;++j){
        int d = lane + j*64;
        out[(size_t)row*DD + d] = __float2bfloat16((v[j]-mean)*rstd*wget(w,mode,woff+d));
    }
}

// ---------------- MFMA GEMM: C[M,N] = A[M,K] @ W[N,K]^T ----------------
// A bf16 row-major. W fp32 (mode0) or bf16 (mode1) row-major [N,K], element offset woff.
// 128x128 tile, BK=32, 4 waves x (4x4) 16x16x32 bf16 MFMA frags.
// EPI: 0 = bf16 store Cb, 1 = fp32 += C (residual), 2 = gelu -> bf16 Cb
template<int EPI>
__global__ __launch_bounds__(256) void gemm_mfma(const bf16* __restrict__ A,
        const void* __restrict__ W, size_t woff, float* __restrict__ C, bf16* __restrict__ Cb,
        int M, int N, int K, const int* __restrict__ flag){
    int mode = flag[0];
    __shared__ short As[128*32];
    __shared__ short Ws[128*32];
    int tid = threadIdx.x;
    int m0 = blockIdx.y * 128;
    int n0 = blockIdx.x * 128;
    int lane = tid & 63, wave = tid >> 6;
    int wm = (wave & 1) * 64, wn = (wave >> 1) * 64;
    int quad = lane >> 4, l16 = lane & 15;

    f32x4 acc[4][4] = {};

    // staging role: thread stages row ra (0..127), k-half ha (0 or 16): 16 elems (32B)
    int ra = tid >> 1;
    int ha = (tid & 1) * 16;

    for (int k0 = 0; k0 < K; k0 += 32){
        __syncthreads();
        // stage A (bf16): 2x16B load + 2x ds_write_b128
        {
            const uint4* gp = (const uint4*)(A + (size_t)(m0+ra)*K + k0 + ha);
            uint4 v0 = gp[0], v1 = gp[1];
            *(uint4*)&As[ra*32 + ha]     = v0;
            *(uint4*)&As[ra*32 + ha + 8] = v1;
        }
        // stage W with dtype dispatch
        if (mode == 0){
            const float4* wp = (const float4*)((const float*)W + woff + (size_t)(n0+ra)*K + k0 + ha);
            float4 f0 = wp[0], f1 = wp[1], f2 = wp[2], f3 = wp[3];
            union { short s[16]; uint4 u[2]; } cv;
            const float* ff = (const float*)&f0;
            float tmp[16] = {f0.x,f0.y,f0.z,f0.w, f1.x,f1.y,f1.z,f1.w,
                             f2.x,f2.y,f2.z,f2.w, f3.x,f3.y,f3.z,f3.w};
            (void)ff;
            #pragma unroll
            for (int k=0;k<16;++k) cv.s[k] = __bfloat16_as_short(__float2bfloat16(tmp[k]));
            *(uint4*)&Ws[ra*32 + ha]     = cv.u[0];
            *(uint4*)&Ws[ra*32 + ha + 8] = cv.u[1];
        } else {
            const uint4* wp = (const uint4*)((const bf16*)W + woff + (size_t)(n0+ra)*K + k0 + ha);
            uint4 v0 = wp[0], v1 = wp[1];
            *(uint4*)&Ws[ra*32 + ha]     = v0;
            *(uint4*)&Ws[ra*32 + ha + 8] = v1;
        }
        __syncthreads();

        bf16x8 af[4], bf[4];
        #pragma unroll
        for (int mi=0;mi<4;++mi)
            af[mi] = *(const bf16x8*)&As[(wm + mi*16 + l16)*32 + quad*8];
        #pragma unroll
        for (int ni=0;ni<4;++ni)
            bf[ni] = *(const bf16x8*)&Ws[(wn + ni*16 + l16)*32 + quad*8];
        #pragma unroll
        for (int mi=0;mi<4;++mi)
            #pragma unroll
            for (int ni=0;ni<4;++ni)
                acc[mi][ni] = __builtin_amdgcn_mfma_f32_16x16x32_bf16(af[mi], bf[ni], acc[mi][ni], 0, 0, 0);
    }

    // epilogue: D row m = quad*4+reg, col n = l16
    #pragma unroll
    for (int mi=0;mi<4;++mi){
        #pragma unroll
        for (int ni=0;ni<4;++ni){
            int mg = m0 + wm + mi*16 + quad*4;
            int ng = n0 + wn + ni*16 + l16;
            #pragma unroll
            for (int reg=0;reg<4;++reg){
                float val = acc[mi][ni][reg];
                size_t off = (size_t)(mg+reg)*N + ng;
                if (EPI==0){
                    Cb[off] = __float2bfloat16(val);
                } else if (EPI==1){
                    C[off] += val;
                } else {
                    float xx = val;
                    float u = 0.7978845608028654f*(xx + 0.044715f*xx*xx*xx);
                    Cb[off] = __float2bfloat16(0.5f*xx*(1.0f+tanhf(u)));
                }
            }
        }
    }
}

// ---------------- VALU GEMM (kept for logits: N=99) ----------------
// EPI 3 = fp32 store C
template<int EPI>
__global__ __launch_bounds__(256) void gemm_nt(const bf16* __restrict__ A,
        const void* __restrict__ W, size_t woff, float* __restrict__ C, bf16* __restrict__ Cb,
        int M, int N, int K, const int* __restrict__ flag){
    int mode = flag[0];
    __shared__ float As[16][64];
    __shared__ float Wt[16][64];
    int m0 = blockIdx.y * 64;
    int n0 = blockIdx.x * 64;
    int t = threadIdx.x;
    int tx = t & 15, ty = t >> 4;
    float acc[4][4] = {};
    int am = t >> 2;
    int ak = (t & 3) * 4;

    for (int k0 = 0; k0 < K; k0 += 16){
        {
            const __hip_bfloat162* ap = (const __hip_bfloat162*)(A + (size_t)(m0+am)*K + k0 + ak);
            __hip_bfloat162 p0 = ap[0], p1 = ap[1];
            float2 f0 = __bfloat1622float2(p0), f1 = __bfloat1622float2(p1);
            As[ak+0][am]=f0.x; As[ak+1][am]=f0.y; As[ak+2][am]=f1.x; As[ak+3][am]=f1.y;
        }
        int wn = n0 + am;
        if (wn < N){
            size_t off = woff + (size_t)wn*K + k0 + ak;
            if (mode == 0){
                float4 wv = *(const float4*)((const float*)W + off);
                Wt[ak+0][am]=wv.x; Wt[ak+1][am]=wv.y; Wt[ak+2][am]=wv.z; Wt[ak+3][am]=wv.w;
            } else {
                const __hip_bfloat162* wp = (const __hip_bfloat162*)((const bf16*)W + off);
                __hip_bfloat162 p0 = wp[0], p1 = wp[1];
                float2 f0 = __bfloat1622float2(p0), f1 = __bfloat1622float2(p1);
                Wt[ak+0][am]=f0.x; Wt[ak+1][am]=f0.y; Wt[ak+2][am]=f1.x; Wt[ak+3][am]=f1.y;
            }
        } else {
            Wt[ak+0][am]=0.f; Wt[ak+1][am]=0.f; Wt[ak+2][am]=0.f; Wt[ak+3][am]=0.f;
        }
        __syncthreads();
        #pragma unroll
        for (int kk=0;kk<16;++kk){
            float a[4], b[4];
            #pragma unroll
            for (int i=0;i<4;++i) a[i]=As[kk][ty*4+i];
            #pragma unroll
            for (int j=0;j<4;++j) b[j]=Wt[kk][tx*4+j];
            #pragma unroll
            for (int i=0;i<4;++i)
                #pragma unroll
                for (int j=0;j<4;++j)
                    acc[i][j] += a[i]*b[j];
        }
        __syncthreads();
    }

    #pragma unroll
    for (int i=0;i<4;++i){
        int m = m0 + ty*4 + i;
        #pragma unroll
        for (int j=0;j<4;++j){
            int n = n0 + tx*4 + j;
            if (n >= N) continue;
            C[(size_t)m*N+n] = acc[i][j];
        }
    }
}

// ---------------- attention: tiled flash, one wg per (b,h,qtile64) ----------------
__global__ __launch_bounds__(256) void attn_kernel2(const bf16* __restrict__ qkv,
                                                    bf16* __restrict__ y){
    __shared__ float Qst[64*68];   // Q^T: [d][q], pre-scaled
    __shared__ float KPs[64*68];   // K^T: [d][j]; reused as P: [q][j]
    __shared__ float Vs [64*68];   // V:   [j][d]

    int tid = threadIdx.x;
    int tx = tid & 15, ty = tid >> 4;
    int bi = blockIdx.x;
    int qt = 31 - (bi & 31);       // big tiles first
    int bh = bi >> 5;
    int h = bh & 7;
    int b = bh >> 3;
    int q0 = qt * 64;
    size_t base = (size_t)b * TT * 1536;

    int r  = tid >> 2;
    int dc = (tid & 3) << 4;

    {
        const uint4* gp = (const uint4*)(qkv + base + (size_t)(q0 + r)*1536 + h*64 + dc);
        uint4 w0 = gp[0], w1 = gp[1];
        float f[16];
        unpack8(w0, f); unpack8(w1, f+8);
        #pragma unroll
        for (int k=0;k<16;++k) Qst[(dc+k)*68 + r] = f[k] * 0.125f;
    }

    float acc[4][4] = {};
    float mrow[4] = {-1e30f,-1e30f,-1e30f,-1e30f};
    float lrow[4] = {0.f,0.f,0.f,0.f};

    int jbmax = qt + 1; if (jbmax > 31) jbmax = 31;

    for (int jb = 0; jb <= jbmax; ++jb){
        int j0 = jb * 64;
        __syncthreads();
        {
            const uint4* gp = (const uint4*)(qkv + base + (size_t)(j0 + r)*1536 + DD + h*64 + dc);
            uint4 w0 = gp[0], w1 = gp[1];
            float f[16];
            unpack8(w0, f); unpack8(w1, f+8);
            #pragma unroll
            for (int k=0;k<16;++k) KPs[(dc+k)*68 + r] = f[k];
        }
        {
            const uint4* gp = (const uint4*)(qkv + base + (size_t)(j0 + r)*1536 + 2*DD + h*64 + dc);
            uint4 w0 = gp[0], w1 = gp[1];
            float f[16];
            unpack8(w0, f); unpack8(w1, f+8);
            #pragma unroll
            for (int k4=0;k4<4;++k4)
                *(float4*)&Vs[r*68 + dc + k4*4] = *(float4*)&f[k4*4];
        }
        __syncthreads();

        float s[4][4] = {};
        #pragma unroll 8
        for (int d=0; d<64; ++d){
            float a[4], bb[4];
            *(float4*)a  = *(float4*)&Qst[d*68 + ty*4];
            *(float4*)bb = *(float4*)&KPs[d*68 + tx*4];
            #pragma unroll
            for (int i=0;i<4;++i)
                #pragma unroll
                for (int j=0;j<4;++j)
                    s[i][j] += a[i]*bb[j];
        }

        if (j0 + 63 > q0 + OFFS){
            #pragma unroll
            for (int i=0;i<4;++i){
                int qg = q0 + ty*4 + i;
                #pragma unroll
                for (int j=0;j<4;++j){
                    if (j0 + tx*4 + j > qg + OFFS) s[i][j] = -1e30f;
                }
            }
        }

        float bm[4], rs[4], alpha[4];
        #pragma unroll
        for (int i=0;i<4;++i)
            bm[i] = fmaxf(fmaxf(s[i][0], s[i][1]), fmaxf(s[i][2], s[i][3]));
        #pragma unroll
        for (int o=1;o<16;o<<=1){
            #pragma unroll
            for (int i=0;i<4;++i) bm[i] = fmaxf(bm[i], __shfl_xor(bm[i], o));
        }
        #pragma unroll
        for (int i=0;i<4;++i){
            float nm = fmaxf(mrow[i], bm[i]);
            alpha[i] = __expf(mrow[i] - nm);
            mrow[i] = nm;
            rs[i] = 0.f;
            #pragma unroll
            for (int j=0;j<4;++j){
                s[i][j] = __expf(s[i][j] - nm);
                rs[i] += s[i][j];
            }
        }
        #pragma unroll
        for (int o=1;o<16;o<<=1){
            #pragma unroll
            for (int i=0;i<4;++i) rs[i] += __shfl_xor(rs[i], o);
        }
        #pragma unroll
        for (int i=0;i<4;++i){
            lrow[i] = lrow[i]*alpha[i] + rs[i];
            #pragma unroll
            for (int j=0;j<4;++j) acc[i][j] *= alpha[i];
        }

        __syncthreads();
        #pragma unroll
        for (int i=0;i<4;++i)
            *(float4*)&KPs[(ty*4+i)*68 + tx*4] = *(float4*)&s[i][0];
        __syncthreads();

        #pragma unroll 8
        for (int j64=0; j64<64; ++j64){
            float vb[4];
            *(float4*)vb = *(float4*)&Vs[j64*68 + tx*4];
            float p[4];
            #pragma unroll
            for (int i=0;i<4;++i) p[i] = KPs[(ty*4+i)*68 + j64];
            #pragma unroll
            for (int i=0;i<4;++i)
                #pragma unroll
                for (int j=0;j<4;++j)
                    acc[i][j] += p[i]*vb[j];
        }
    }

    #pragma unroll
    for (int i=0;i<4;++i){
        int qg = q0 + ty*4 + i;
        float inv = 1.0f / lrow[i];
        bf16* yp = y + ((size_t)b*TT + qg)*DD + h*64 + tx*4;
        #pragma unroll
        for (int j=0;j<4;++j) yp[j] = __float2bfloat16(acc[i][j]*inv);
    }
}

// ---------------- loss (fp32 logits) ----------------
__global__ void loss_kernel(const float* __restrict__ logits, const int* __restrict__ targets,
                            float* __restrict__ acc){
    int row = blockIdx.x;
    int lane = threadIdx.x;
    int yt = targets[row];
    const float* lp = logits + (size_t)row*VV;
    float e0 = (lane < VV)    ? lp[lane]    : -1e30f;
    float e1 = (lane+64 < VV) ? lp[lane+64] : -1e30f;
    float mx = fmaxf(e0,e1);
    #pragma unroll
    for (int o=32;o;o>>=1) mx = fmaxf(mx, __shfl_xor(mx,o));
    float se = 0.f;
    if (lane < VV)    se += __expf(e0-mx);
    if (lane+64 < VV) se += __expf(e1-mx);
    #pragma unroll
    for (int o=32;o;o>>=1) se += __shfl_xor(se,o);
    if (lane == 0 && yt >= 0){
        float wi = (yt>=78 && yt<96) ? 1.0f : (yt==96 ? 0.1f : 0.0f);
        if (wi > 0.f){
            float ly = lp[yt];
            float nll = -(ly - mx - logf(se));
            atomicAdd(&acc[0], wi*nll);
            atomicAdd(&acc[1], wi);
        }
    }
}

__global__ void fin_loss(const float* __restrict__ acc, float* __restrict__ out){
    out[0] = acc[0]/acc[1];
}

// ---------------- launch ----------------
extern "C" void kernel_launch(void* const* d_in, const int* in_sizes, int n_in,
                              void* d_out, int out_size, void* d_ws, size_t ws_size,
                              hipStream_t stream){
    const int*  idx     = (const int*) d_in[0];
    const int*  targets = (const int*) d_in[1];
    const void* wte     = d_in[2];
    const void* wpe     = d_in[3];
    const void* ln1_w   = d_in[4];
    const void* attn_w  = d_in[5];
    const void* proj_w  = d_in[6];
    const void* ln2_w   = d_in[7];
    const void* fc_w    = d_in[8];
    const void* fcp_w   = d_in[9];
    const void* lnf_w   = d_in[10];
    float* out = (float*)d_out;   // fp32: logits [8192,99] then loss [1]

    float* ws   = (float*)d_ws;
    float* ACC  = ws;
    int*   FLAG = (int*)(ws + 4);
    bf16*  Hb   = (bf16*)(ws + 16);                      // [8192,512] bf16
    float* X    = ws + 16 + 2097152;                     // [8192,512] fp32
    bf16*  BIG  = (bf16*)(ws + 16 + 2097152 + 4194304);  // [8192,2048] bf16

    const size_t ATT_S = (size_t)3*DD*DD;
    const size_t PRJ_S = (size_t)DD*DD;
    const size_t FC_S  = (size_t)4*DD*DD;

    init_kernel<<<1,1,0,stream>>>((const unsigned int*)ln1_w, ACC, FLAG);
    embed_kernel<<<ROWS,256,0,stream>>>(idx, wte, wpe, X, FLAG);
    for (int l=0; l<LL; ++l){
        ln_kernel<<<ROWS,64,0,stream>>>(X, ln1_w, (size_t)l*DD, Hb, FLAG);
        gemm_mfma<0><<<dim3(3*DD/128, ROWS/128),256,0,stream>>>(Hb, attn_w, (size_t)l*ATT_S,
                                                                nullptr, BIG, ROWS, 3*DD, DD, FLAG);
        attn_kernel2<<<dim3(BB*HH*32),256,0,stream>>>(BIG, Hb);
        gemm_mfma<1><<<dim3(DD/128, ROWS/128),256,0,stream>>>(Hb, proj_w, (size_t)l*PRJ_S,
                                                              X, nullptr, ROWS, DD, DD, FLAG);
        ln_kernel<<<ROWS,64,0,stream>>>(X, ln2_w, (size_t)l*DD, Hb, FLAG);
        gemm_mfma<2><<<dim3(4*DD/128, ROWS/128),256,0,stream>>>(Hb, fc_w, (size_t)l*FC_S,
                                                                nullptr, BIG, ROWS, 4*DD, DD, FLAG);
        gemm_mfma<1><<<dim3(DD/128, ROWS/128),256,0,stream>>>(BIG, fcp_w, (size_t)l*FC_S,
                                                              X, nullptr, ROWS, DD, 4*DD, FLAG);
    }
    ln_kernel<<<ROWS,64,0,stream>>>(X, lnf_w, 0, Hb, FLAG);
    gemm_nt<3><<<dim3((VV+63)/64, ROWS/64),256,0,stream>>>(Hb, wte, 0, out, nullptr, ROWS, VV, DD, FLAG);
    loss_kernel<<<ROWS,64,0,stream>>>(out, targets, ACC);
    fin_loss<<<1,1,0,stream>>>(ACC, out + (size_t)ROWS*VV);
}

// Round 7
// 2590.002 us; speedup vs baseline: 12.6952x; 1.6486x over previous
//
#include <hip/hip_runtime.h>
#include <hip/hip_bf16.h>
#include <math.h>

#define BB 4
#define TT 2048
#define VV 99
#define DD 512
#define HH 8
#define LL 6
#define DHH 64
#define OFFS 28
#define ROWS (BB*TT)   // 8192

typedef __hip_bfloat16 bf16;
typedef __attribute__((ext_vector_type(8))) short bf16x8;
typedef __attribute__((ext_vector_type(4))) float f32x4;

__device__ __forceinline__ float b2f(bf16 x){ return __bfloat162float(x); }

// mode-dispatched weight read from a raw base + element offset (mode1 = bf16 inputs)
__device__ __forceinline__ float wget(const void* w, int mode, size_t i){
    return mode ? b2f(((const bf16*)w)[i]) : ((const float*)w)[i];
}

// ---------------- init ----------------
__global__ void init_kernel(const unsigned int* __restrict__ ln1_bits, float* __restrict__ acc,
                            int* __restrict__ flag){
    acc[0] = 0.f; acc[1] = 0.f;
    flag[0] = (ln1_bits[0] == 0x3F800000u) ? 0 : 1;
}

// ---------------- embedding ----------------
__global__ void embed_kernel(const int* __restrict__ idx, const void* __restrict__ wte,
                             const void* __restrict__ wpe, float* __restrict__ x,
                             const int* __restrict__ flag){
    int mode = flag[0];
    int row = blockIdx.x;
    int t = row % TT;
    int tok = idx[row];
    int i = threadIdx.x;
    #pragma unroll
    for (int j = 0; j < 2; ++j){
        int d = i + j*256;
        x[(size_t)row*DD + d] = wget(wte, mode, (size_t)tok*DD + d)
                              + wget(wpe, mode, (size_t)t*DD + d);
    }
}

// ---------------- layernorm: fp32 in, bf16 out ----------------
__global__ void ln_kernel(const float* __restrict__ x, const void* __restrict__ w,
                          size_t woff, bf16* __restrict__ out, const int* __restrict__ flag){
    int mode = flag[0];
    int row = blockIdx.x;
    int lane = threadIdx.x; // 64
    const float* xr = x + (size_t)row*DD;
    float v[8];
    float s = 0.f;
    #pragma unroll
    for (int j=0;j<8;++j){ v[j] = xr[lane + j*64]; s += v[j]; }
    #pragma unroll
    for (int o=32;o;o>>=1) s += __shfl_xor(s,o);
    float mean = s * (1.0f/DD);
    float vs = 0.f;
    #pragma unroll
    for (int j=0;j<8;++j){ float d = v[j]-mean; vs += d*d; }
    #pragma unroll
    for (int o=32;o;o>>=1) vs += __shfl_xor(vs,o);
    float rstd = rsqrtf(vs*(1.0f/DD) + 1e-5f);
    #pragma unroll
    for (int j=0;j<8;++j){
        int d = lane + j*64;
        out[(size_t)row*DD + d] = __float2bfloat16((v[j]-mean)*rstd*wget(w,mode,woff+d));
    }
}

// ---------------- MFMA GEMM: C[M,N] = A[M,K] @ W[N,K]^T ----------------
// 128x128 tile, BK=32, 4 waves x (4x4) 16x16x32 bf16 MFMA frags.
// EPI: 0 = bf16 store Cb, 1 = fp32 += C (residual), 2 = gelu -> bf16 Cb
template<int EPI>
__global__ __launch_bounds__(256) void gemm_mfma(const bf16* __restrict__ A,
        const void* __restrict__ W, size_t woff, float* __restrict__ C, bf16* __restrict__ Cb,
        int M, int N, int K, const int* __restrict__ flag){
    int mode = flag[0];
    __shared__ short As[128*32];
    __shared__ short Ws[128*32];
    int tid = threadIdx.x;
    int m0 = blockIdx.y * 128;
    int n0 = blockIdx.x * 128;
    int lane = tid & 63, wave = tid >> 6;
    int wm = (wave & 1) * 64, wn = (wave >> 1) * 64;
    int quad = lane >> 4, l16 = lane & 15;

    f32x4 acc[4][4] = {};

    int ra = tid >> 1;
    int ha = (tid & 1) * 16;

    for (int k0 = 0; k0 < K; k0 += 32){
        __syncthreads();
        {
            const uint4* gp = (const uint4*)(A + (size_t)(m0+ra)*K + k0 + ha);
            uint4 v0 = gp[0], v1 = gp[1];
            *(uint4*)&As[ra*32 + ha]     = v0;
            *(uint4*)&As[ra*32 + ha + 8] = v1;
        }
        if (mode == 0){
            const float4* wp = (const float4*)((const float*)W + woff + (size_t)(n0+ra)*K + k0 + ha);
            float4 f0 = wp[0], f1 = wp[1], f2 = wp[2], f3 = wp[3];
            union { short s[16]; uint4 u[2]; } cv;
            float tmp[16] = {f0.x,f0.y,f0.z,f0.w, f1.x,f1.y,f1.z,f1.w,
                             f2.x,f2.y,f2.z,f2.w, f3.x,f3.y,f3.z,f3.w};
            #pragma unroll
            for (int k=0;k<16;++k) cv.s[k] = __bfloat16_as_short(__float2bfloat16(tmp[k]));
            *(uint4*)&Ws[ra*32 + ha]     = cv.u[0];
            *(uint4*)&Ws[ra*32 + ha + 8] = cv.u[1];
        } else {
            const uint4* wp = (const uint4*)((const bf16*)W + woff + (size_t)(n0+ra)*K + k0 + ha);
            uint4 v0 = wp[0], v1 = wp[1];
            *(uint4*)&Ws[ra*32 + ha]     = v0;
            *(uint4*)&Ws[ra*32 + ha + 8] = v1;
        }
        __syncthreads();

        bf16x8 af[4], bf[4];
        #pragma unroll
        for (int mi=0;mi<4;++mi)
            af[mi] = *(const bf16x8*)&As[(wm + mi*16 + l16)*32 + quad*8];
        #pragma unroll
        for (int ni=0;ni<4;++ni)
            bf[ni] = *(const bf16x8*)&Ws[(wn + ni*16 + l16)*32 + quad*8];
        #pragma unroll
        for (int mi=0;mi<4;++mi)
            #pragma unroll
            for (int ni=0;ni<4;++ni)
                acc[mi][ni] = __builtin_amdgcn_mfma_f32_16x16x32_bf16(af[mi], bf[ni], acc[mi][ni], 0, 0, 0);
    }

    #pragma unroll
    for (int mi=0;mi<4;++mi){
        #pragma unroll
        for (int ni=0;ni<4;++ni){
            int mg = m0 + wm + mi*16 + quad*4;
            int ng = n0 + wn + ni*16 + l16;
            #pragma unroll
            for (int reg=0;reg<4;++reg){
                float val = acc[mi][ni][reg];
                size_t off = (size_t)(mg+reg)*N + ng;
                if (EPI==0){
                    Cb[off] = __float2bfloat16(val);
                } else if (EPI==1){
                    C[off] += val;
                } else {
                    float xx = val;
                    float u = 0.7978845608028654f*(xx + 0.044715f*xx*xx*xx);
                    Cb[off] = __float2bfloat16(0.5f*xx*(1.0f+tanhf(u)));
                }
            }
        }
    }
}

// ---------------- VALU GEMM (kept for logits: N=99), fp32 store ----------------
__global__ __launch_bounds__(256) void gemm_nt3(const bf16* __restrict__ A,
        const void* __restrict__ W, size_t woff, float* __restrict__ C,
        int M, int N, int K, const int* __restrict__ flag){
    int mode = flag[0];
    __shared__ float As[16][64];
    __shared__ float Wt[16][64];
    int m0 = blockIdx.y * 64;
    int n0 = blockIdx.x * 64;
    int t = threadIdx.x;
    int tx = t & 15, ty = t >> 4;
    float acc[4][4] = {};
    int am = t >> 2;
    int ak = (t & 3) * 4;

    for (int k0 = 0; k0 < K; k0 += 16){
        {
            const __hip_bfloat162* ap = (const __hip_bfloat162*)(A + (size_t)(m0+am)*K + k0 + ak);
            __hip_bfloat162 p0 = ap[0], p1 = ap[1];
            float2 f0 = __bfloat1622float2(p0), f1 = __bfloat1622float2(p1);
            As[ak+0][am]=f0.x; As[ak+1][am]=f0.y; As[ak+2][am]=f1.x; As[ak+3][am]=f1.y;
        }
        int wn = n0 + am;
        if (wn < N){
            size_t off = woff + (size_t)wn*K + k0 + ak;
            if (mode == 0){
                float4 wv = *(const float4*)((const float*)W + off);
                Wt[ak+0][am]=wv.x; Wt[ak+1][am]=wv.y; Wt[ak+2][am]=wv.z; Wt[ak+3][am]=wv.w;
            } else {
                const __hip_bfloat162* wp = (const __hip_bfloat162*)((const bf16*)W + off);
                __hip_bfloat162 p0 = wp[0], p1 = wp[1];
                float2 f0 = __bfloat1622float2(p0), f1 = __bfloat1622float2(p1);
                Wt[ak+0][am]=f0.x; Wt[ak+1][am]=f0.y; Wt[ak+2][am]=f1.x; Wt[ak+3][am]=f1.y;
            }
        } else {
            Wt[ak+0][am]=0.f; Wt[ak+1][am]=0.f; Wt[ak+2][am]=0.f; Wt[ak+3][am]=0.f;
        }
        __syncthreads();
        #pragma unroll
        for (int kk=0;kk<16;++kk){
            float a[4], b[4];
            #pragma unroll
            for (int i=0;i<4;++i) a[i]=As[kk][ty*4+i];
            #pragma unroll
            for (int j=0;j<4;++j) b[j]=Wt[kk][tx*4+j];
            #pragma unroll
            for (int i=0;i<4;++i)
                #pragma unroll
                for (int j=0;j<4;++j)
                    acc[i][j] += a[i]*b[j];
        }
        __syncthreads();
    }

    #pragma unroll
    for (int i=0;i<4;++i){
        int m = m0 + ty*4 + i;
        #pragma unroll
        for (int j=0;j<4;++j){
            int n = n0 + tx*4 + j;
            if (n >= N) continue;
            C[(size_t)m*N+n] = acc[i][j];
        }
    }
}

// ---------------- attention v3: MFMA flash, one wg per (b,h,qtile64) ----------------
// qkv bf16 [B,T,3D]; y bf16 [B,T,D]
// 4 waves; wave w owns query rows [w*16, w*16+16).
// LDS tiles stride 72 elems (144B) to break power-of-2 bank aliasing.
#define AST 72
__global__ __launch_bounds__(256, 4) void attn_mfma(const bf16* __restrict__ qkv,
                                                    bf16* __restrict__ y){
    __shared__ short Qs[64*AST];
    __shared__ short Ks[64*AST];
    __shared__ short Vs[64*AST];
    __shared__ short Ps[4*16*AST];   // per-wave P scratch

    int tid = threadIdx.x;
    int lane = tid & 63, wave = tid >> 6;
    int quad = lane >> 4, l16 = lane & 15;

    int bi = blockIdx.x;
    int qt = 31 - (bi & 31);       // big tiles first
    int bh = bi >> 5;
    int h = bh & 7;
    int b = bh >> 3;
    int q0 = qt * 64;
    size_t base = (size_t)b * TT * 1536;

    int r  = tid >> 2;             // 0..63 staging row
    int dc = (tid & 3) << 4;       // 0,16,32,48

    // stage Q tile (raw bf16, row-major)
    {
        const uint4* gp = (const uint4*)(qkv + base + (size_t)(q0 + r)*1536 + h*64 + dc);
        uint4 v0 = gp[0], v1 = gp[1];
        *(uint4*)&Qs[r*AST + dc]     = v0;
        *(uint4*)&Qs[r*AST + dc + 8] = v1;
    }

    f32x4 O[4] = {};                       // O[dt]: C-layout, row=quad*4+reg, col=dt*16+l16
    float mr[4] = {-1e30f,-1e30f,-1e30f,-1e30f};
    float lr[4] = {0.f,0.f,0.f,0.f};

    int jbmax = qt + 1; if (jbmax > 31) jbmax = 31;

    for (int jb = 0; jb <= jbmax; ++jb){
        int j0 = jb * 64;
        __syncthreads();
        // stage K and V tiles (row-major bf16)
        {
            const uint4* gp = (const uint4*)(qkv + base + (size_t)(j0 + r)*1536 + DD + h*64 + dc);
            uint4 v0 = gp[0], v1 = gp[1];
            *(uint4*)&Ks[r*AST + dc]     = v0;
            *(uint4*)&Ks[r*AST + dc + 8] = v1;
        }
        {
            const uint4* gp = (const uint4*)(qkv + base + (size_t)(j0 + r)*1536 + 2*DD + h*64 + dc);
            uint4 v0 = gp[0], v1 = gp[1];
            *(uint4*)&Vs[r*AST + dc]     = v0;
            *(uint4*)&Vs[r*AST + dc + 8] = v1;
        }
        __syncthreads();

        // S = Q K^T  (wave's 16 rows x 64 cols)
        bf16x8 aq0 = *(const bf16x8*)&Qs[(wave*16 + l16)*AST + quad*8];
        bf16x8 aq1 = *(const bf16x8*)&Qs[(wave*16 + l16)*AST + 32 + quad*8];
        f32x4 s[4] = {};
        #pragma unroll
        for (int ni=0; ni<4; ++ni){
            bf16x8 bk0 = *(const bf16x8*)&Ks[(ni*16 + l16)*AST + quad*8];
            bf16x8 bk1 = *(const bf16x8*)&Ks[(ni*16 + l16)*AST + 32 + quad*8];
            s[ni] = __builtin_amdgcn_mfma_f32_16x16x32_bf16(aq0, bk0, s[ni], 0, 0, 0);
            s[ni] = __builtin_amdgcn_mfma_f32_16x16x32_bf16(aq1, bk1, s[ni], 0, 0, 0);
        }

        // scale + mask + online softmax (C-layout: row=quad*4+reg, col=ni*16+l16)
        float sc[4][4];
        bool boundary = (j0 + 63 > q0 + OFFS);
        #pragma unroll
        for (int ni=0; ni<4; ++ni){
            #pragma unroll
            for (int reg=0; reg<4; ++reg){
                float v = s[ni][reg] * 0.125f;
                if (boundary){
                    int qg = q0 + wave*16 + quad*4 + reg;
                    int jg = j0 + ni*16 + l16;
                    if (jg > qg + OFFS) v = -1e30f;
                }
                sc[ni][reg] = v;
            }
        }
        float bm[4], alpha[4], rs[4];
        #pragma unroll
        for (int reg=0; reg<4; ++reg)
            bm[reg] = fmaxf(fmaxf(sc[0][reg], sc[1][reg]), fmaxf(sc[2][reg], sc[3][reg]));
        #pragma unroll
        for (int o=1;o<16;o<<=1){
            #pragma unroll
            for (int reg=0; reg<4; ++reg) bm[reg] = fmaxf(bm[reg], __shfl_xor(bm[reg], o));
        }
        #pragma unroll
        for (int reg=0; reg<4; ++reg){
            float nm = fmaxf(mr[reg], bm[reg]);
            alpha[reg] = __expf(mr[reg] - nm);
            mr[reg] = nm;
            rs[reg] = 0.f;
            #pragma unroll
            for (int ni=0; ni<4; ++ni){
                sc[ni][reg] = __expf(sc[ni][reg] - nm);
                rs[reg] += sc[ni][reg];
            }
        }
        #pragma unroll
        for (int o=1;o<16;o<<=1){
            #pragma unroll
            for (int reg=0; reg<4; ++reg) rs[reg] += __shfl_xor(rs[reg], o);
        }
        #pragma unroll
        for (int reg=0; reg<4; ++reg){
            lr[reg] = lr[reg]*alpha[reg] + rs[reg];
            #pragma unroll
            for (int dt=0; dt<4; ++dt) O[dt][reg] *= alpha[reg];
        }

        // write P (bf16) to per-wave LDS scratch, C-layout -> A-layout round trip
        short* pw = &Ps[wave*16*AST];
        #pragma unroll
        for (int ni=0; ni<4; ++ni)
            #pragma unroll
            for (int reg=0; reg<4; ++reg)
                pw[(quad*4+reg)*AST + ni*16 + l16] = __bfloat16_as_short(__float2bfloat16(sc[ni][reg]));

        // PV: A = P (rows = wave's 16 q), B = V (B[k=j][n=d] gathered as b16)
        bf16x8 ap0 = *(const bf16x8*)&pw[l16*AST + quad*8];
        bf16x8 ap1 = *(const bf16x8*)&pw[l16*AST + 32 + quad*8];
        #pragma unroll
        for (int dt=0; dt<4; ++dt){
            bf16x8 bv0, bv1;
            #pragma unroll
            for (int i=0;i<8;++i){
                bv0[i] = Vs[(quad*8 + i)*AST + dt*16 + l16];
                bv1[i] = Vs[(32 + quad*8 + i)*AST + dt*16 + l16];
            }
            O[dt] = __builtin_amdgcn_mfma_f32_16x16x32_bf16(ap0, bv0, O[dt], 0, 0, 0);
            O[dt] = __builtin_amdgcn_mfma_f32_16x16x32_bf16(ap1, bv1, O[dt], 0, 0, 0);
        }
    }

    // epilogue: O / l -> y
    float inv[4];
    #pragma unroll
    for (int reg=0; reg<4; ++reg) inv[reg] = 1.0f / lr[reg];
    #pragma unroll
    for (int dt=0; dt<4; ++dt){
        #pragma unroll
        for (int reg=0; reg<4; ++reg){
            int qg = q0 + wave*16 + quad*4 + reg;
            y[((size_t)b*TT + qg)*DD + h*64 + dt*16 + l16] =
                __float2bfloat16(O[dt][reg] * inv[reg]);
        }
    }
}

// ---------------- loss (fp32 logits) ----------------
__global__ void loss_kernel(const float* __restrict__ logits, const int* __restrict__ targets,
                            float* __restrict__ acc){
    int row = blockIdx.x;
    int lane = threadIdx.x;
    int yt = targets[row];
    const float* lp = logits + (size_t)row*VV;
    float e0 = (lane < VV)    ? lp[lane]    : -1e30f;
    float e1 = (lane+64 < VV) ? lp[lane+64] : -1e30f;
    float mx = fmaxf(e0,e1);
    #pragma unroll
    for (int o=32;o;o>>=1) mx = fmaxf(mx, __shfl_xor(mx,o));
    float se = 0.f;
    if (lane < VV)    se += __expf(e0-mx);
    if (lane+64 < VV) se += __expf(e1-mx);
    #pragma unroll
    for (int o=32;o;o>>=1) se += __shfl_xor(se,o);
    if (lane == 0 && yt >= 0){
        float wi = (yt>=78 && yt<96) ? 1.0f : (yt==96 ? 0.1f : 0.0f);
        if (wi > 0.f){
            float ly = lp[yt];
            float nll = -(ly - mx - logf(se));
            atomicAdd(&acc[0], wi*nll);
            atomicAdd(&acc[1], wi);
        }
    }
}

__global__ void fin_loss(const float* __restrict__ acc, float* __restrict__ out){
    out[0] = acc[0]/acc[1];
}

// ---------------- launch ----------------
extern "C" void kernel_launch(void* const* d_in, const int* in_sizes, int n_in,
                              void* d_out, int out_size, void* d_ws, size_t ws_size,
                              hipStream_t stream){
    const int*  idx     = (const int*) d_in[0];
    const int*  targets = (const int*) d_in[1];
    const void* wte     = d_in[2];
    const void* wpe     = d_in[3];
    const void* ln1_w   = d_in[4];
    const void* attn_w  = d_in[5];
    const void* proj_w  = d_in[6];
    const void* ln2_w   = d_in[7];
    const void* fc_w    = d_in[8];
    const void* fcp_w   = d_in[9];
    const void* lnf_w   = d_in[10];
    float* out = (float*)d_out;   // fp32: logits [8192,99] then loss [1]

    float* ws   = (float*)d_ws;
    float* ACC  = ws;
    int*   FLAG = (int*)(ws + 4);
    bf16*  Hb   = (bf16*)(ws + 16);                      // [8192,512] bf16
    float* X    = ws + 16 + 2097152;                     // [8192,512] fp32
    bf16*  BIG  = (bf16*)(ws + 16 + 2097152 + 4194304);  // [8192,2048] bf16

    const size_t ATT_S = (size_t)3*DD*DD;
    const size_t PRJ_S = (size_t)DD*DD;
    const size_t FC_S  = (size_t)4*DD*DD;

    init_kernel<<<1,1,0,stream>>>((const unsigned int*)ln1_w, ACC, FLAG);
    embed_kernel<<<ROWS,256,0,stream>>>(idx, wte, wpe, X, FLAG);
    for (int l=0; l<LL; ++l){
        ln_kernel<<<ROWS,64,0,stream>>>(X, ln1_w, (size_t)l*DD, Hb, FLAG);
        gemm_mfma<0><<<dim3(3*DD/128, ROWS/128),256,0,stream>>>(Hb, attn_w, (size_t)l*ATT_S,
                                                                nullptr, BIG, ROWS, 3*DD, DD, FLAG);
        attn_mfma<<<dim3(BB*HH*32),256,0,stream>>>(BIG, Hb);
        gemm_mfma<1><<<dim3(DD/128, ROWS/128),256,0,stream>>>(Hb, proj_w, (size_t)l*PRJ_S,
                                                              X, nullptr, ROWS, DD, DD, FLAG);
        ln_kernel<<<ROWS,64,0,stream>>>(X, ln2_w, (size_t)l*DD, Hb, FLAG);
        gemm_mfma<2><<<dim3(4*DD/128, ROWS/128),256,0,stream>>>(Hb, fc_w, (size_t)l*FC_S,
                                                                nullptr, BIG, ROWS, 4*DD, DD, FLAG);
        gemm_mfma<1><<<dim3(DD/128, ROWS/128),256,0,stream>>>(BIG, fcp_w, (size_t)l*FC_S,
                                                              X, nullptr, ROWS, DD, 4*DD, FLAG);
    }
    ln_kernel<<<ROWS,64,0,stream>>>(X, lnf_w, 0, Hb, FLAG);
    gemm_nt3<<<dim3((VV+63)/64, ROWS/64),256,0,stream>>>(Hb, wte, 0, out, ROWS, VV, DD, FLAG);
    loss_kernel<<<ROWS,64,0,stream>>>(out, targets, ACC);
    fin_loss<<<1,1,0,stream>>>(ACC, out + (size_t)ROWS*VV);
}